// Round 14
// baseline (839.642 us; speedup 1.0000x reference)
//
#include <hip/hip_runtime.h>

#define NNODES 50000
#define DIN 128
#define DHID 128
#define DOUT 128
#define NEG_SLOPE 0.01f
#define NT 25000   // 50000 nodes / 2 nodes-per-tile (64-row tiles)
#define GG 512     // persistent grid: 2 blocks per CU (the occupancy fix)

typedef _Float16 f16x8 __attribute__((ext_vector_type(8)));
typedef _Float16 f16x4 __attribute__((ext_vector_type(4)));
typedef _Float16 f16x2 __attribute__((ext_vector_type(2)));
typedef float f32x4 __attribute__((ext_vector_type(4)));

__device__ __forceinline__ f16x2 pkrtz(float a, float b) {
    return __builtin_bit_cast(f16x2, __builtin_amdgcn_cvt_pkrtz(a, b));
}

// d_ws layout (halves):
//  WqB hi: [ct(8)][g(4)][l(64)][8]   = 16384 halves
//  WqB lo: 16384
//  WwB hi: [ct(8)][g(8)][l(64)][8]   = 32768 halves
//  WwB lo: 32768
#define WS_WQ_HI 0
#define WS_WQ_LO 16384
#define WS_WW_HI 32768
#define WS_WW_LO 65536

// ---------------------------------------------------------------- kernel 0
// Convert weights to fp16 hi/lo fragment slabs.
// Fragment convention (mfma_f32_16x16x32_f16):
//   A: row = l&15, k = (l>>4)*8 + j
//   B: col = l&15, k = (l>>4)*8 + j
//   D: col = l&15, row = (l>>4)*4 + r
__global__ void convert_weights(const float* __restrict__ Wq,
                                const float* __restrict__ Ww,
                                _Float16* __restrict__ ws) {
    int id = blockIdx.x * 256 + threadIdx.x;
    if (id < 2048) {  // Wq slots: B[k][col] = Wq[col][k]
        int s  = id;
        int l  = s & 63;
        int g  = (s >> 6) & 3;
        int ct = s >> 8;
        int col = ct * 16 + (l & 15);
        int k0  = g * 32 + (l >> 4) * 8;
        const float* src = Wq + col * DIN + k0;
        f16x8 vh, vl;
#pragma unroll
        for (int j = 0; j < 8; ++j) {
            float v = src[j];
            _Float16 h = (_Float16)v;
            vh[j] = h;
            vl[j] = (_Float16)(v - (float)h);
        }
        *(f16x8*)(ws + WS_WQ_HI + s * 8) = vh;
        *(f16x8*)(ws + WS_WQ_LO + s * 8) = vl;
    } else if (id < 2048 + 4096) {  // Ww slots: B2[k][o] = Ww[o][k]
        int s  = id - 2048;
        int l  = s & 63;
        int g  = (s >> 6) & 7;
        int ct = s >> 9;
        int col = ct * 16 + (l & 15);
        int k0  = g * 32 + (l >> 4) * 8;
        const float* src = Ww + col * (DIN + DHID) + k0;
        f16x8 vh, vl;
#pragma unroll
        for (int j = 0; j < 8; ++j) {
            float v = src[j];
            _Float16 h = (_Float16)v;
            vh[j] = h;
            vl[j] = (_Float16)(v - (float)h);
        }
        *(f16x8*)(ws + WS_WW_HI + s * 8) = vh;
        *(f16x8*)(ws + WS_WW_LO + s * 8) = vl;
    }
}

// ---------------------------------------------------------------- kernel 1
// GEMM1 + leaky + alpha-weighted mean -> hagg (= d_out).
// R13 reg-staged skeleton with the OCCUPANCY fix:
//  - every prior persistent variant ran GG=256 = 1 block/CU = 2 waves/SIMD
//    (grid-capped, not VGPR-capped: R12 profile VGPR_Count=88). The ~4us
//    tile clock vs 2.6us delivery need = unhidden ds_read/VALU latency at
//    2 waves/SIMD. Four falsified theories (pattern/barriers/depth/
//    mechanism) all shared this constant.
//  - tile = 64 rows (2 nodes, 32KB); As[2][8192] = 64KB/block ->
//    2 blocks/CU by LDS; __launch_bounds__(512,4) caps VGPR at 128
//    (budget ~124) -> 16 waves/CU = 4 waves/SIMD. Two blocks interleave:
//    one block's barrier stall is covered by the other's waves.
//  - staging: reg-staged (global->VGPR->ds_write), no counted vmcnt
//    (compiler auto-waits on reg deps). Write-side XOR swizzle
//    row*512 + (o ^ ((row&7)<<4)); COMPUTE reads with same involution.
//  - per wave: 1 node; epilogue pure shfl over kg; alpha prefetched.
__global__ __launch_bounds__(512, 4) void gemm1_agg(
    const float* __restrict__ hng,    // [NNODES*32][128]
    const float* __restrict__ alpha,  // [NNODES*32]
    const float* __restrict__ bq,     // [128]
    const _Float16* __restrict__ ws,
    float* __restrict__ hagg)         // [NNODES][128]
{
    __shared__ float As[2][8192];  // 2 x 32KB tile buffers (64KB total)

    const int tid  = threadIdx.x;
    const int l    = tid & 63;
    const int wid  = tid >> 6;         // 0..7
    const int rgrp = wid >> 2;         // 0..1  (node within tile)
    const int cgrp = wid & 3;          // 0..3  (32-col group)
    const int r16  = l & 15;
    const int kg   = l >> 4;

    const _Float16* wqh = ws + WS_WQ_HI;
    const _Float16* wql = ws + WS_WQ_LO;

    // ---- permanent B fragments: 4 k-frags x 2 col-tiles, hi+lo (64 VGPR)
    f16x8 bh[4][2], bl[4][2];
#pragma unroll
    for (int kf = 0; kf < 4; ++kf)
#pragma unroll
        for (int ct = 0; ct < 2; ++ct) {
            int off = (((cgrp * 2 + ct) * 4 + kf) * 64 + l) * 8;
            bh[kf][ct] = *(const f16x8*)(wqh + off);
            bl[kf][ct] = *(const f16x8*)(wql + off);
        }

    // ---- staging geometry. Instr i covers tile rows (wid*4+i)*2+(l>>5),
    // 512B each; global read linear (coalesced 1KB/instr); LDS write at
    // XOR-swizzled byte offset (involution matches COMPUTE's read XOR).
    int gro[4], dwo[4];
#pragma unroll
    for (int i = 0; i < 4; ++i) {
        int row = (wid * 4 + i) * 2 + (l >> 5);
        int o   = (l & 31) * 16;
        gro[i]  = row * 128 + (l & 31) * 4;            // float offset
        dwo[i]  = row * 512 + (o ^ ((row & 7) << 4));  // byte offset
    }

    float bqv[2];
#pragma unroll
    for (int ct = 0; ct < 2; ++ct)
        bqv[ct] = bq[cgrp * 32 + ct * 16 + r16];

    f32x4 sA[4];            // staged tile regs (16 VGPR)
    f32x4 av4[2], av4n[2];  // alpha cur/next for this wave's node (16 VGPR)

#define LOADR(Tb)                                                             \
    do {                                                                      \
        const float* gb_ = hng + (long)(Tb) * 64 * DIN;                       \
        _Pragma("unroll")                                                     \
        for (int i_ = 0; i_ < 4; ++i_)                                        \
            sA[i_] = *(const f32x4*)(gb_ + gro[i_]);                          \
        _Pragma("unroll")                                                     \
        for (int rt_ = 0; rt_ < 2; ++rt_)                                     \
            av4n[rt_] = *(const f32x4*)(alpha + (long)(Tb) * 64 +             \
                                        rgrp * 32 + rt_ * 16 + kg * 4);       \
    } while (0)

#define DSWRITE(s)                                                            \
    do {                                                                      \
        char* lb_ = (char*)&As[s][0];                                         \
        _Pragma("unroll")                                                     \
        for (int i_ = 0; i_ < 4; ++i_)                                        \
            *(f32x4*)(lb_ + dwo[i_]) = sA[i_];                                \
    } while (0)

#define COMPUTE(s)                                                            \
    do {                                                                      \
        _Pragma("unroll")                                                     \
        for (int rt_ = 0; rt_ < 2; ++rt_) {                                   \
            int row_ = rgrp * 32 + rt_ * 16 + r16;                            \
            int asw_ = (row_ & 7) << 4;                                       \
            const char* sb_ = (const char*)&As[s][0] + row_ * 512;            \
            _Pragma("unroll")                                                 \
            for (int kf_ = 0; kf_ < 4; ++kf_) {                               \
                int kb_ = kf_ * 128 + kg * 32;                                \
                f32x4 v0_ = *(const f32x4*)(sb_ + ((kb_ + 0) ^ asw_));        \
                f32x4 v1_ = *(const f32x4*)(sb_ + ((kb_ + 16) ^ asw_));       \
                f16x2 p0_ = pkrtz(v0_[0], v0_[1]);                            \
                f16x2 p1_ = pkrtz(v0_[2], v0_[3]);                            \
                f16x2 p2_ = pkrtz(v1_[0], v1_[1]);                            \
                f16x2 p3_ = pkrtz(v1_[2], v1_[3]);                            \
                f16x8 ah_;                                                    \
                ah_[0] = p0_[0]; ah_[1] = p0_[1];                             \
                ah_[2] = p1_[0]; ah_[3] = p1_[1];                             \
                ah_[4] = p2_[0]; ah_[5] = p2_[1];                             \
                ah_[6] = p3_[0]; ah_[7] = p3_[1];                             \
                _Pragma("unroll")                                             \
                for (int ct_ = 0; ct_ < 2; ++ct_) {                           \
                    acc[rt_][ct_] = __builtin_amdgcn_mfma_f32_16x16x32_f16(   \
                        ah_, bh[kf_][ct_], acc[rt_][ct_], 0, 0, 0);           \
                    acc[rt_][ct_] = __builtin_amdgcn_mfma_f32_16x16x32_f16(   \
                        ah_, bl[kf_][ct_], acc[rt_][ct_], 0, 0, 0);           \
                }                                                             \
            }                                                                 \
        }                                                                     \
    } while (0)

    long t = blockIdx.x;

    // ---- prologue: load tile t to regs, write buf0 (auto vmcnt waits)
    LOADR(t);
    DSWRITE(0);
#pragma unroll
    for (int rt = 0; rt < 2; ++rt) av4[rt] = av4n[rt];
    asm volatile("s_waitcnt lgkmcnt(0)" ::: "memory");
    __builtin_amdgcn_s_barrier();
    __builtin_amdgcn_sched_barrier(0);

    int cur = 0;
    for (;;) {
        const bool last = (t + GG >= NT);
        const long tn   = last ? t : t + GG;   // clamped prefetch target

        // ---- issue next tile's loads first (overlap compute below)
        LOADR(tn);
        __builtin_amdgcn_sched_barrier(0);

        f32x4 acc[2][2];
#pragma unroll
        for (int i = 0; i < 2; ++i)
#pragma unroll
            for (int j = 0; j < 2; ++j) acc[i][j] = (f32x4){0.f, 0.f, 0.f, 0.f};

        COMPUTE(cur);
        __builtin_amdgcn_sched_barrier(0);

        // ---- epilogue: +bq, leaky, *alpha, reduce this wave's node
        {
            float part[2] = {0.f, 0.f};
            float apart = 0.f;
#pragma unroll
            for (int rt = 0; rt < 2; ++rt)
#pragma unroll
                for (int r = 0; r < 4; ++r) {
                    float aw = av4[rt][r];
                    apart += aw;
#pragma unroll
                    for (int ct = 0; ct < 2; ++ct) {
                        float v = acc[rt][ct][r] + bqv[ct];
                        v = (v >= 0.f) ? v : NEG_SLOPE * v;
                        part[ct] += aw * v;
                    }
                }
            apart += __shfl_xor(apart, 16);
            apart += __shfl_xor(apart, 32);
#pragma unroll
            for (int ct = 0; ct < 2; ++ct) {
                part[ct] += __shfl_xor(part[ct], 16);
                part[ct] += __shfl_xor(part[ct], 32);
            }
            if (l < 16) {
                long node = t * 2 + rgrp;
                float den = apart;
                if (den == 0.f) den = 1.f;
#pragma unroll
                for (int ct = 0; ct < 2; ++ct)
                    hagg[node * DHID + cgrp * 32 + ct * 16 + l] =
                        part[ct] / den;
            }
        }
        __builtin_amdgcn_sched_barrier(0);

        // ---- write next tile into the other buffer (compiler inserts the
        //      vmcnt wait on sA deps); publish with lgkm0 + barrier.
        DSWRITE(cur ^ 1);
#pragma unroll
        for (int rt = 0; rt < 2; ++rt) av4[rt] = av4n[rt];
        asm volatile("s_waitcnt lgkmcnt(0)" ::: "memory");
        __builtin_amdgcn_s_barrier();
        __builtin_amdgcn_sched_barrier(0);

        if (last) break;
        t   = tn;
        cur ^= 1;
    }
    asm volatile("s_waitcnt vmcnt(0)" ::: "memory");  // drain stores

#undef LOADR
#undef DSWRITE
#undef COMPUTE
}

// ---------------------------------------------------------------- kernel 2
// GEMM2: out = normalize(leaky(concat(h_node, hagg) @ Ww^T + bw))
// Tile: 128 nodes x 128 out, K=256 in 8 chunks of 32. hagg lives in `out`.
// A single-f16 via pkrtz; B hi+lo; 2 MFMA terms. (unchanged)
__global__ __launch_bounds__(256, 2) void gemm2_norm(
    const float* __restrict__ hnode,  // [NNODES][128]
    const float* __restrict__ bw,     // [128]
    const _Float16* __restrict__ ws,
    float* __restrict__ out)          // [NNODES][128], holds hagg on entry
{
    __shared__ _Float16 Ahi[8 * 520];
    __shared__ _Float16 Bhi[8 * 512];
    __shared__ _Float16 Blo[8 * 512];
    __shared__ float bw_s[128];
    __shared__ float nbuf[2][128];

    const int tid = threadIdx.x;
    const int l   = tid & 63;
    const int wid = tid >> 6;
    const int wr  = wid >> 1, wc = wid & 1;
    const long NB = (long)blockIdx.x * 128;

    if (tid < 128) bw_s[tid] = bw[tid];

    f32x4 acc[4][4];
#pragma unroll
    for (int i = 0; i < 4; ++i)
#pragma unroll
        for (int j = 0; j < 4; ++j) acc[i][j] = (f32x4){0.f, 0.f, 0.f, 0.f};

    const _Float16* wwh = ws + WS_WW_HI;
    const _Float16* wwl = ws + WS_WW_LO;

    for (int c = 0; c < 8; ++c) {
        __syncthreads();
        // ---- stage A: 128 nodes x 32 k of concat(h_node, hagg), f16 single
#pragma unroll
        for (int p = 0; p < 4; ++p) {
            int rl = p * 32 + (tid >> 3);
            long n = NB + rl;
            if (n > NNODES - 1) n = NNODES - 1;  // tail clamp (stores guarded)
            int kw = (tid & 7) * 4;       // within-chunk k
            int kgl = c * 32 + kw;        // global k in 0..255
            const float* g = (kgl < 128) ? (hnode + n * DIN + kgl)
                                         : (out + n * DHID + (kgl - 128));
            f32x4 v = *(const f32x4*)g;
            f16x2 p0 = pkrtz(v[0], v[1]);
            f16x2 p1 = pkrtz(v[2], v[3]);
            f16x4 vh;
            vh[0] = p0[0]; vh[1] = p0[1]; vh[2] = p1[0]; vh[3] = p1[1];
            int lw  = (rl & 15) | (((kw >> 3) & 3) << 4);
            int s   = rl >> 4;
            int off = s * 520 + lw * 8 + (kw & 7);
            *(f16x4*)(Ahi + off) = vh;
        }
        // ---- stage B slabs (g = c)
#pragma unroll
        for (int i = 0; i < 4; ++i) {
            int id = i * 256 + tid;
            int sb = id >> 6;
            int ls = id & 63;
            if (sb < 8) {
                *(f16x8*)(Bhi + sb * 512 + ls * 8) =
                    *(const f16x8*)(wwh + ((sb * 8 + c) * 64 + ls) * 8);
            } else {
                int ct = sb - 8;
                *(f16x8*)(Blo + ct * 512 + ls * 8) =
                    *(const f16x8*)(wwl + ((ct * 8 + c) * 64 + ls) * 8);
            }
        }
        __syncthreads();
        // ---- compute
        f16x8 ah[4], bh[4], bl[4];
#pragma unroll
        for (int rt = 0; rt < 4; ++rt) {
            int s = wr * 4 + rt;
            ah[rt] = *(const f16x8*)(Ahi + s * 520 + l * 8);
        }
#pragma unroll
        for (int ct = 0; ct < 4; ++ct) {
            int s = wc * 4 + ct;
            bh[ct] = *(const f16x8*)(Bhi + s * 512 + l * 8);
            bl[ct] = *(const f16x8*)(Blo + s * 512 + l * 8);
        }
#pragma unroll
        for (int rt = 0; rt < 4; ++rt)
#pragma unroll
            for (int ct = 0; ct < 4; ++ct) {
                acc[rt][ct] = __builtin_amdgcn_mfma_f32_16x16x32_f16(ah[rt], bh[ct], acc[rt][ct], 0, 0, 0);
                acc[rt][ct] = __builtin_amdgcn_mfma_f32_16x16x32_f16(ah[rt], bl[ct], acc[rt][ct], 0, 0, 0);
            }
    }

    // ---- epilogue: +bw, leaky, row L2-norm (128 cols), safediv, store
    const int grp = l >> 4;
#pragma unroll
    for (int rt = 0; rt < 4; ++rt)
#pragma unroll
        for (int ct = 0; ct < 4; ++ct)
#pragma unroll
            for (int r = 0; r < 4; ++r) {
                int col = wc * 64 + ct * 16 + (l & 15);
                float v = acc[rt][ct][r] + bw_s[col];
                acc[rt][ct][r] = (v >= 0.f) ? v : NEG_SLOPE * v;
            }
    float ssq[4][4];
#pragma unroll
    for (int rt = 0; rt < 4; ++rt)
#pragma unroll
        for (int r = 0; r < 4; ++r) {
            float s = 0.f;
#pragma unroll
            for (int ct = 0; ct < 4; ++ct) s += acc[rt][ct][r] * acc[rt][ct][r];
            s += __shfl_xor(s, 1);
            s += __shfl_xor(s, 2);
            s += __shfl_xor(s, 4);
            s += __shfl_xor(s, 8);
            ssq[rt][r] = s;  // sum over this wave's 64 cols
        }
    if ((l & 15) == 0) {
#pragma unroll
        for (int rt = 0; rt < 4; ++rt)
#pragma unroll
            for (int r = 0; r < 4; ++r)
                nbuf[wc][wr * 64 + rt * 16 + grp * 4 + r] = ssq[rt][r];
    }
    __syncthreads();
#pragma unroll
    for (int rt = 0; rt < 4; ++rt)
#pragma unroll
        for (int r = 0; r < 4; ++r) {
            int rowl = wr * 64 + rt * 16 + grp * 4 + r;
            long n = NB + rowl;
            if (n < NNODES) {
                float nrm = sqrtf(nbuf[0][rowl] + nbuf[1][rowl]);
                if (nrm == 0.f) nrm = 1.f;
#pragma unroll
                for (int ct = 0; ct < 4; ++ct) {
                    int col = wc * 64 + ct * 16 + (l & 15);
                    out[n * DOUT + col] = acc[rt][ct][r] / nrm;
                }
            }
        }
}

// ---------------------------------------------------------------- launcher
extern "C" void kernel_launch(void* const* d_in, const int* in_sizes, int n_in,
                              void* d_out, int out_size, void* d_ws, size_t ws_size,
                              hipStream_t stream) {
    const float* h_node  = (const float*)d_in[0];
    const float* h_ngbrs = (const float*)d_in[1];
    const float* alpha   = (const float*)d_in[2];
    const float* Wq      = (const float*)d_in[3];
    const float* bq      = (const float*)d_in[4];
    const float* Ww      = (const float*)d_in[5];
    const float* bw      = (const float*)d_in[6];
    float* out   = (float*)d_out;
    _Float16* ws = (_Float16*)d_ws;

    convert_weights<<<24, 256, 0, stream>>>(Wq, Ww, ws);
    gemm1_agg<<<GG, 512, 0, stream>>>(h_ngbrs, alpha, bq, ws, out);
    // ceil(50000/128) = 391 node tiles
    gemm2_norm<<<391, 256, 0, stream>>>(h_node, bw, ws, out);
}

// Round 15
// 223.262 us; speedup vs baseline: 3.7608x; 3.7608x over previous
//
#include <hip/hip_runtime.h>

#define NNODES 50000
#define DIN 128
#define DHID 128
#define DOUT 128
#define NEG_SLOPE 0.01f
#define NT 25000   // 50000 nodes / 2 nodes-per-tile (64-row tiles)
#define GG 512     // persistent grid: 2 blocks per CU

typedef _Float16 f16x8 __attribute__((ext_vector_type(8)));
typedef _Float16 f16x4 __attribute__((ext_vector_type(4)));
typedef _Float16 f16x2 __attribute__((ext_vector_type(2)));
typedef float f32x4 __attribute__((ext_vector_type(4)));

__device__ __forceinline__ f16x2 pkrtz(float a, float b) {
    return __builtin_bit_cast(f16x2, __builtin_amdgcn_cvt_pkrtz(a, b));
}

// d_ws layout (halves):
//  WqB hi: [ct(8)][g(4)][l(64)][8]   = 16384 halves
//  WqB lo: 16384
//  WwB hi: [ct(8)][g(8)][l(64)][8]   = 32768 halves
//  WwB lo: 32768
#define WS_WQ_HI 0
#define WS_WQ_LO 16384
#define WS_WW_HI 32768
#define WS_WW_LO 65536

// ---------------------------------------------------------------- kernel 0
// Convert weights to fp16 hi/lo fragment slabs.
// Fragment convention (mfma_f32_16x16x32_f16):
//   A: row = l&15, k = (l>>4)*8 + j
//   B: col = l&15, k = (l>>4)*8 + j
//   D: col = l&15, row = (l>>4)*4 + r
__global__ void convert_weights(const float* __restrict__ Wq,
                                const float* __restrict__ Ww,
                                _Float16* __restrict__ ws) {
    int id = blockIdx.x * 256 + threadIdx.x;
    if (id < 2048) {  // Wq slots: B[k][col] = Wq[col][k]
        int s  = id;
        int l  = s & 63;
        int g  = (s >> 6) & 3;
        int ct = s >> 8;
        int col = ct * 16 + (l & 15);
        int k0  = g * 32 + (l >> 4) * 8;
        const float* src = Wq + col * DIN + k0;
        f16x8 vh, vl;
#pragma unroll
        for (int j = 0; j < 8; ++j) {
            float v = src[j];
            _Float16 h = (_Float16)v;
            vh[j] = h;
            vl[j] = (_Float16)(v - (float)h);
        }
        *(f16x8*)(ws + WS_WQ_HI + s * 8) = vh;
        *(f16x8*)(ws + WS_WQ_LO + s * 8) = vl;
    } else if (id < 2048 + 4096) {  // Ww slots: B2[k][o] = Ww[o][k]
        int s  = id - 2048;
        int l  = s & 63;
        int g  = (s >> 6) & 7;
        int ct = s >> 9;
        int col = ct * 16 + (l & 15);
        int k0  = g * 32 + (l >> 4) * 8;
        const float* src = Ww + col * (DIN + DHID) + k0;
        f16x8 vh, vl;
#pragma unroll
        for (int j = 0; j < 8; ++j) {
            float v = src[j];
            _Float16 h = (_Float16)v;
            vh[j] = h;
            vl[j] = (_Float16)(v - (float)h);
        }
        *(f16x8*)(ws + WS_WW_HI + s * 8) = vh;
        *(f16x8*)(ws + WS_WW_LO + s * 8) = vl;
    }
}

// ---------------------------------------------------------------- kernel 1
// GEMM1 + leaky + alpha-weighted mean -> hagg (= d_out).
// R14 retry with CORRECT launch bounds. R14's __launch_bounds__(512,4)
// was interpreted as min-4-BLOCKS/CU -> 8 waves/SIMD -> 64-VGPR cap ->
// ~60 VGPR spilled to scratch (profile: VGPR=64, FETCH 2.6GB = 3.2x
// input, MfmaUtil 5%). The occupancy experiment never ran.
// (512,2) caps VGPR at >=128 (~120 needed -> no spill); LDS 64KB/block
// still admits 2 blocks/CU = 16 waves/CU = 4 waves/SIMD — double all
// prior variants; the two blocks' barrier stalls interleave.
//  - tile = 64 rows (2 nodes, 32KB); As[2][8192]; reg-staged
//    (global->VGPR->ds_write), no counted vmcnt (compiler auto-waits).
//  - write-side XOR swizzle row*512 + (o ^ ((row&7)<<4)); COMPUTE reads
//    with the same involution.
//  - per wave: 1 node; epilogue pure shfl over kg; alpha prefetched.
__global__ __launch_bounds__(512, 2) void gemm1_agg(
    const float* __restrict__ hng,    // [NNODES*32][128]
    const float* __restrict__ alpha,  // [NNODES*32]
    const float* __restrict__ bq,     // [128]
    const _Float16* __restrict__ ws,
    float* __restrict__ hagg)         // [NNODES][128]
{
    __shared__ float As[2][8192];  // 2 x 32KB tile buffers (64KB total)

    const int tid  = threadIdx.x;
    const int l    = tid & 63;
    const int wid  = tid >> 6;         // 0..7
    const int rgrp = wid >> 2;         // 0..1  (node within tile)
    const int cgrp = wid & 3;          // 0..3  (32-col group)
    const int r16  = l & 15;
    const int kg   = l >> 4;

    const _Float16* wqh = ws + WS_WQ_HI;
    const _Float16* wql = ws + WS_WQ_LO;

    // ---- permanent B fragments: 4 k-frags x 2 col-tiles, hi+lo (64 VGPR)
    f16x8 bh[4][2], bl[4][2];
#pragma unroll
    for (int kf = 0; kf < 4; ++kf)
#pragma unroll
        for (int ct = 0; ct < 2; ++ct) {
            int off = (((cgrp * 2 + ct) * 4 + kf) * 64 + l) * 8;
            bh[kf][ct] = *(const f16x8*)(wqh + off);
            bl[kf][ct] = *(const f16x8*)(wql + off);
        }

    // ---- staging geometry. Instr i covers tile rows (wid*4+i)*2+(l>>5),
    // 512B each; global read linear (coalesced 1KB/instr); LDS write at
    // XOR-swizzled byte offset (involution matches COMPUTE's read XOR).
    int gro[4], dwo[4];
#pragma unroll
    for (int i = 0; i < 4; ++i) {
        int row = (wid * 4 + i) * 2 + (l >> 5);
        int o   = (l & 31) * 16;
        gro[i]  = row * 128 + (l & 31) * 4;            // float offset
        dwo[i]  = row * 512 + (o ^ ((row & 7) << 4));  // byte offset
    }

    float bqv[2];
#pragma unroll
    for (int ct = 0; ct < 2; ++ct)
        bqv[ct] = bq[cgrp * 32 + ct * 16 + r16];

    f32x4 sA[4];            // staged tile regs (16 VGPR)
    f32x4 av4[2], av4n[2];  // alpha cur/next for this wave's node (16 VGPR)

#define LOADR(Tb)                                                             \
    do {                                                                      \
        const float* gb_ = hng + (long)(Tb) * 64 * DIN;                       \
        _Pragma("unroll")                                                     \
        for (int i_ = 0; i_ < 4; ++i_)                                        \
            sA[i_] = *(const f32x4*)(gb_ + gro[i_]);                          \
        _Pragma("unroll")                                                     \
        for (int rt_ = 0; rt_ < 2; ++rt_)                                     \
            av4n[rt_] = *(const f32x4*)(alpha + (long)(Tb) * 64 +             \
                                        rgrp * 32 + rt_ * 16 + kg * 4);       \
    } while (0)

#define DSWRITE(s)                                                            \
    do {                                                                      \
        char* lb_ = (char*)&As[s][0];                                         \
        _Pragma("unroll")                                                     \
        for (int i_ = 0; i_ < 4; ++i_)                                        \
            *(f32x4*)(lb_ + dwo[i_]) = sA[i_];                                \
    } while (0)

#define COMPUTE(s)                                                            \
    do {                                                                      \
        _Pragma("unroll")                                                     \
        for (int rt_ = 0; rt_ < 2; ++rt_) {                                   \
            int row_ = rgrp * 32 + rt_ * 16 + r16;                            \
            int asw_ = (row_ & 7) << 4;                                       \
            const char* sb_ = (const char*)&As[s][0] + row_ * 512;            \
            _Pragma("unroll")                                                 \
            for (int kf_ = 0; kf_ < 4; ++kf_) {                               \
                int kb_ = kf_ * 128 + kg * 32;                                \
                f32x4 v0_ = *(const f32x4*)(sb_ + ((kb_ + 0) ^ asw_));        \
                f32x4 v1_ = *(const f32x4*)(sb_ + ((kb_ + 16) ^ asw_));       \
                f16x2 p0_ = pkrtz(v0_[0], v0_[1]);                            \
                f16x2 p1_ = pkrtz(v0_[2], v0_[3]);                            \
                f16x2 p2_ = pkrtz(v1_[0], v1_[1]);                            \
                f16x2 p3_ = pkrtz(v1_[2], v1_[3]);                            \
                f16x8 ah_;                                                    \
                ah_[0] = p0_[0]; ah_[1] = p0_[1];                             \
                ah_[2] = p1_[0]; ah_[3] = p1_[1];                             \
                ah_[4] = p2_[0]; ah_[5] = p2_[1];                             \
                ah_[6] = p3_[0]; ah_[7] = p3_[1];                             \
                _Pragma("unroll")                                             \
                for (int ct_ = 0; ct_ < 2; ++ct_) {                           \
                    acc[rt_][ct_] = __builtin_amdgcn_mfma_f32_16x16x32_f16(   \
                        ah_, bh[kf_][ct_], acc[rt_][ct_], 0, 0, 0);           \
                    acc[rt_][ct_] = __builtin_amdgcn_mfma_f32_16x16x32_f16(   \
                        ah_, bl[kf_][ct_], acc[rt_][ct_], 0, 0, 0);           \
                }                                                             \
            }                                                                 \
        }                                                                     \
    } while (0)

    long t = blockIdx.x;

    // ---- prologue: load tile t to regs, write buf0 (auto vmcnt waits)
    LOADR(t);
    DSWRITE(0);
#pragma unroll
    for (int rt = 0; rt < 2; ++rt) av4[rt] = av4n[rt];
    asm volatile("s_waitcnt lgkmcnt(0)" ::: "memory");
    __builtin_amdgcn_s_barrier();
    __builtin_amdgcn_sched_barrier(0);

    int cur = 0;
    for (;;) {
        const bool last = (t + GG >= NT);
        const long tn   = last ? t : t + GG;   // clamped prefetch target

        // ---- issue next tile's loads first (overlap compute below)
        LOADR(tn);
        __builtin_amdgcn_sched_barrier(0);

        f32x4 acc[2][2];
#pragma unroll
        for (int i = 0; i < 2; ++i)
#pragma unroll
            for (int j = 0; j < 2; ++j) acc[i][j] = (f32x4){0.f, 0.f, 0.f, 0.f};

        COMPUTE(cur);
        __builtin_amdgcn_sched_barrier(0);

        // ---- epilogue: +bq, leaky, *alpha, reduce this wave's node
        {
            float part[2] = {0.f, 0.f};
            float apart = 0.f;
#pragma unroll
            for (int rt = 0; rt < 2; ++rt)
#pragma unroll
                for (int r = 0; r < 4; ++r) {
                    float aw = av4[rt][r];
                    apart += aw;
#pragma unroll
                    for (int ct = 0; ct < 2; ++ct) {
                        float v = acc[rt][ct][r] + bqv[ct];
                        v = (v >= 0.f) ? v : NEG_SLOPE * v;
                        part[ct] += aw * v;
                    }
                }
            apart += __shfl_xor(apart, 16);
            apart += __shfl_xor(apart, 32);
#pragma unroll
            for (int ct = 0; ct < 2; ++ct) {
                part[ct] += __shfl_xor(part[ct], 16);
                part[ct] += __shfl_xor(part[ct], 32);
            }
            if (l < 16) {
                long node = t * 2 + rgrp;
                float den = apart;
                if (den == 0.f) den = 1.f;
#pragma unroll
                for (int ct = 0; ct < 2; ++ct)
                    hagg[node * DHID + cgrp * 32 + ct * 16 + l] =
                        part[ct] / den;
            }
        }
        __builtin_amdgcn_sched_barrier(0);

        // ---- write next tile into the other buffer (compiler inserts the
        //      vmcnt wait on sA deps); publish with lgkm0 + barrier.
        DSWRITE(cur ^ 1);
#pragma unroll
        for (int rt = 0; rt < 2; ++rt) av4[rt] = av4n[rt];
        asm volatile("s_waitcnt lgkmcnt(0)" ::: "memory");
        __builtin_amdgcn_s_barrier();
        __builtin_amdgcn_sched_barrier(0);

        if (last) break;
        t   = tn;
        cur ^= 1;
    }
    asm volatile("s_waitcnt vmcnt(0)" ::: "memory");  // drain stores

#undef LOADR
#undef DSWRITE
#undef COMPUTE
}

// ---------------------------------------------------------------- kernel 2
// GEMM2: out = normalize(leaky(concat(h_node, hagg) @ Ww^T + bw))
// Tile: 128 nodes x 128 out, K=256 in 8 chunks of 32. hagg lives in `out`.
// A single-f16 via pkrtz; B hi+lo; 2 MFMA terms. (unchanged)
__global__ __launch_bounds__(256, 2) void gemm2_norm(
    const float* __restrict__ hnode,  // [NNODES][128]
    const float* __restrict__ bw,     // [128]
    const _Float16* __restrict__ ws,
    float* __restrict__ out)          // [NNODES][128], holds hagg on entry
{
    __shared__ _Float16 Ahi[8 * 520];
    __shared__ _Float16 Bhi[8 * 512];
    __shared__ _Float16 Blo[8 * 512];
    __shared__ float bw_s[128];
    __shared__ float nbuf[2][128];

    const int tid = threadIdx.x;
    const int l   = tid & 63;
    const int wid = tid >> 6;
    const int wr  = wid >> 1, wc = wid & 1;
    const long NB = (long)blockIdx.x * 128;

    if (tid < 128) bw_s[tid] = bw[tid];

    f32x4 acc[4][4];
#pragma unroll
    for (int i = 0; i < 4; ++i)
#pragma unroll
        for (int j = 0; j < 4; ++j) acc[i][j] = (f32x4){0.f, 0.f, 0.f, 0.f};

    const _Float16* wwh = ws + WS_WW_HI;
    const _Float16* wwl = ws + WS_WW_LO;

    for (int c = 0; c < 8; ++c) {
        __syncthreads();
        // ---- stage A: 128 nodes x 32 k of concat(h_node, hagg), f16 single
#pragma unroll
        for (int p = 0; p < 4; ++p) {
            int rl = p * 32 + (tid >> 3);
            long n = NB + rl;
            if (n > NNODES - 1) n = NNODES - 1;  // tail clamp (stores guarded)
            int kw = (tid & 7) * 4;       // within-chunk k
            int kgl = c * 32 + kw;        // global k in 0..255
            const float* g = (kgl < 128) ? (hnode + n * DIN + kgl)
                                         : (out + n * DHID + (kgl - 128));
            f32x4 v = *(const f32x4*)g;
            f16x2 p0 = pkrtz(v[0], v[1]);
            f16x2 p1 = pkrtz(v[2], v[3]);
            f16x4 vh;
            vh[0] = p0[0]; vh[1] = p0[1]; vh[2] = p1[0]; vh[3] = p1[1];
            int lw  = (rl & 15) | (((kw >> 3) & 3) << 4);
            int s   = rl >> 4;
            int off = s * 520 + lw * 8 + (kw & 7);
            *(f16x4*)(Ahi + off) = vh;
        }
        // ---- stage B slabs (g = c)
#pragma unroll
        for (int i = 0; i < 4; ++i) {
            int id = i * 256 + tid;
            int sb = id >> 6;
            int ls = id & 63;
            if (sb < 8) {
                *(f16x8*)(Bhi + sb * 512 + ls * 8) =
                    *(const f16x8*)(wwh + ((sb * 8 + c) * 64 + ls) * 8);
            } else {
                int ct = sb - 8;
                *(f16x8*)(Blo + ct * 512 + ls * 8) =
                    *(const f16x8*)(wwl + ((ct * 8 + c) * 64 + ls) * 8);
            }
        }
        __syncthreads();
        // ---- compute
        f16x8 ah[4], bh[4], bl[4];
#pragma unroll
        for (int rt = 0; rt < 4; ++rt) {
            int s = wr * 4 + rt;
            ah[rt] = *(const f16x8*)(Ahi + s * 520 + l * 8);
        }
#pragma unroll
        for (int ct = 0; ct < 4; ++ct) {
            int s = wc * 4 + ct;
            bh[ct] = *(const f16x8*)(Bhi + s * 512 + l * 8);
            bl[ct] = *(const f16x8*)(Blo + s * 512 + l * 8);
        }
#pragma unroll
        for (int rt = 0; rt < 4; ++rt)
#pragma unroll
            for (int ct = 0; ct < 4; ++ct) {
                acc[rt][ct] = __builtin_amdgcn_mfma_f32_16x16x32_f16(ah[rt], bh[ct], acc[rt][ct], 0, 0, 0);
                acc[rt][ct] = __builtin_amdgcn_mfma_f32_16x16x32_f16(ah[rt], bl[ct], acc[rt][ct], 0, 0, 0);
            }
    }

    // ---- epilogue: +bw, leaky, row L2-norm (128 cols), safediv, store
    const int grp = l >> 4;
#pragma unroll
    for (int rt = 0; rt < 4; ++rt)
#pragma unroll
        for (int ct = 0; ct < 4; ++ct)
#pragma unroll
            for (int r = 0; r < 4; ++r) {
                int col = wc * 64 + ct * 16 + (l & 15);
                float v = acc[rt][ct][r] + bw_s[col];
                acc[rt][ct][r] = (v >= 0.f) ? v : NEG_SLOPE * v;
            }
    float ssq[4][4];
#pragma unroll
    for (int rt = 0; rt < 4; ++rt)
#pragma unroll
        for (int r = 0; r < 4; ++r) {
            float s = 0.f;
#pragma unroll
            for (int ct = 0; ct < 4; ++ct) s += acc[rt][ct][r] * acc[rt][ct][r];
            s += __shfl_xor(s, 1);
            s += __shfl_xor(s, 2);
            s += __shfl_xor(s, 4);
            s += __shfl_xor(s, 8);
            ssq[rt][r] = s;  // sum over this wave's 64 cols
        }
    if ((l & 15) == 0) {
#pragma unroll
        for (int rt = 0; rt < 4; ++rt)
#pragma unroll
            for (int r = 0; r < 4; ++r)
                nbuf[wc][wr * 64 + rt * 16 + grp * 4 + r] = ssq[rt][r];
    }
    __syncthreads();
#pragma unroll
    for (int rt = 0; rt < 4; ++rt)
#pragma unroll
        for (int r = 0; r < 4; ++r) {
            int rowl = wr * 64 + rt * 16 + grp * 4 + r;
            long n = NB + rowl;
            if (n < NNODES) {
                float nrm = sqrtf(nbuf[0][rowl] + nbuf[1][rowl]);
                if (nrm == 0.f) nrm = 1.f;
#pragma unroll
                for (int ct = 0; ct < 4; ++ct) {
                    int col = wc * 64 + ct * 16 + (l & 15);
                    out[n * DOUT + col] = acc[rt][ct][r] / nrm;
                }
            }
        }
}

// ---------------------------------------------------------------- launcher
extern "C" void kernel_launch(void* const* d_in, const int* in_sizes, int n_in,
                              void* d_out, int out_size, void* d_ws, size_t ws_size,
                              hipStream_t stream) {
    const float* h_node  = (const float*)d_in[0];
    const float* h_ngbrs = (const float*)d_in[1];
    const float* alpha   = (const float*)d_in[2];
    const float* Wq      = (const float*)d_in[3];
    const float* bq      = (const float*)d_in[4];
    const float* Ww      = (const float*)d_in[5];
    const float* bw      = (const float*)d_in[6];
    float* out   = (float*)d_out;
    _Float16* ws = (_Float16*)d_ws;

    convert_weights<<<24, 256, 0, stream>>>(Wq, Ww, ws);
    gemm1_agg<<<GG, 512, 0, stream>>>(h_ngbrs, alpha, bq, ws, out);
    // ceil(50000/128) = 391 node tiles
    gemm2_norm<<<391, 256, 0, stream>>>(h_node, bw, ws, out);
}

// Round 16
// 220.382 us; speedup vs baseline: 3.8099x; 1.0131x over previous
//
#include <hip/hip_runtime.h>

#define NNODES 50000
#define DIN 128
#define DHID 128
#define DOUT 128
#define NEG_SLOPE 0.01f
#define NT 25000   // 50000 nodes / 2 nodes-per-tile (64-row tiles)
#define GG 512     // persistent grid: 2 blocks per CU

typedef _Float16 f16x8 __attribute__((ext_vector_type(8)));
typedef _Float16 f16x4 __attribute__((ext_vector_type(4)));
typedef _Float16 f16x2 __attribute__((ext_vector_type(2)));
typedef float f32x4 __attribute__((ext_vector_type(4)));

__device__ __forceinline__ f16x2 pkrtz(float a, float b) {
    return __builtin_bit_cast(f16x2, __builtin_amdgcn_cvt_pkrtz(a, b));
}

// d_ws layout (halves):
//  WqB hi: [ct(8)][g(4)][l(64)][8]   = 16384 halves
//  WqB lo: 16384
//  WwB hi: [ct(8)][g(8)][l(64)][8]   = 32768 halves
//  WwB lo: 32768
#define WS_WQ_HI 0
#define WS_WQ_LO 16384
#define WS_WW_HI 32768
#define WS_WW_LO 65536

// ---------------------------------------------------------------- kernel 0
// Convert weights to fp16 hi/lo fragment slabs.
// Fragment convention (mfma_f32_16x16x32_f16):
//   A: row = l&15, k = (l>>4)*8 + j
//   B: col = l&15, k = (l>>4)*8 + j
//   D: col = l&15, row = (l>>4)*4 + r
__global__ void convert_weights(const float* __restrict__ Wq,
                                const float* __restrict__ Ww,
                                _Float16* __restrict__ ws) {
    int id = blockIdx.x * 256 + threadIdx.x;
    if (id < 2048) {  // Wq slots: B[k][col] = Wq[col][k]
        int s  = id;
        int l  = s & 63;
        int g  = (s >> 6) & 3;
        int ct = s >> 8;
        int col = ct * 16 + (l & 15);
        int k0  = g * 32 + (l >> 4) * 8;
        const float* src = Wq + col * DIN + k0;
        f16x8 vh, vl;
#pragma unroll
        for (int j = 0; j < 8; ++j) {
            float v = src[j];
            _Float16 h = (_Float16)v;
            vh[j] = h;
            vl[j] = (_Float16)(v - (float)h);
        }
        *(f16x8*)(ws + WS_WQ_HI + s * 8) = vh;
        *(f16x8*)(ws + WS_WQ_LO + s * 8) = vl;
    } else if (id < 2048 + 4096) {  // Ww slots: B2[k][o] = Ww[o][k]
        int s  = id - 2048;
        int l  = s & 63;
        int g  = (s >> 6) & 7;
        int ct = s >> 9;
        int col = ct * 16 + (l & 15);
        int k0  = g * 32 + (l >> 4) * 8;
        const float* src = Ww + col * (DIN + DHID) + k0;
        f16x8 vh, vl;
#pragma unroll
        for (int j = 0; j < 8; ++j) {
            float v = src[j];
            _Float16 h = (_Float16)v;
            vh[j] = h;
            vl[j] = (_Float16)(v - (float)h);
        }
        *(f16x8*)(ws + WS_WW_HI + s * 8) = vh;
        *(f16x8*)(ws + WS_WW_LO + s * 8) = vl;
    }
}

// ---------------------------------------------------------------- kernel 1
// GEMM1 + leaky + alpha-weighted mean -> hagg (= d_out).
// R15 best (223us) + ONE change: NON-TEMPORAL loads for the h_ngbrs
// stream. Eight orthogonal schedules all pinned at ~4.4TB/s effective
// read -> the limiter is the read path, not the schedule. h_ngbrs has
// ZERO reuse (read-once 819MB stream) yet always went through L2/L3.
// __builtin_nontemporal_load emits the nt cache hint while keeping
// normal register dependency tracking (no manual vmcnt).
//  - tile = 64 rows (2 nodes, 32KB); As[2][8192] (64KB) -> 2 blocks/CU,
//    4 waves/SIMD; ~120 VGPR under the (512,2) cap (no spill, R15).
//  - reg-staged global->VGPR->ds_write; write-side XOR swizzle
//    row*512 + (o ^ ((row&7)<<4)); COMPUTE reads same involution.
//  - per wave: 1 node; epilogue pure shfl; alpha prefetched (also nt).
__global__ __launch_bounds__(512, 2) void gemm1_agg(
    const float* __restrict__ hng,    // [NNODES*32][128]
    const float* __restrict__ alpha,  // [NNODES*32]
    const float* __restrict__ bq,     // [128]
    const _Float16* __restrict__ ws,
    float* __restrict__ hagg)         // [NNODES][128]
{
    __shared__ float As[2][8192];  // 2 x 32KB tile buffers (64KB total)

    const int tid  = threadIdx.x;
    const int l    = tid & 63;
    const int wid  = tid >> 6;         // 0..7
    const int rgrp = wid >> 2;         // 0..1  (node within tile)
    const int cgrp = wid & 3;          // 0..3  (32-col group)
    const int r16  = l & 15;
    const int kg   = l >> 4;

    const _Float16* wqh = ws + WS_WQ_HI;
    const _Float16* wql = ws + WS_WQ_LO;

    // ---- permanent B fragments: 4 k-frags x 2 col-tiles, hi+lo (64 VGPR)
    f16x8 bh[4][2], bl[4][2];
#pragma unroll
    for (int kf = 0; kf < 4; ++kf)
#pragma unroll
        for (int ct = 0; ct < 2; ++ct) {
            int off = (((cgrp * 2 + ct) * 4 + kf) * 64 + l) * 8;
            bh[kf][ct] = *(const f16x8*)(wqh + off);
            bl[kf][ct] = *(const f16x8*)(wql + off);
        }

    // ---- staging geometry. Instr i covers tile rows (wid*4+i)*2+(l>>5),
    // 512B each; global read linear (coalesced 1KB/instr); LDS write at
    // XOR-swizzled byte offset (involution matches COMPUTE's read XOR).
    int gro[4], dwo[4];
#pragma unroll
    for (int i = 0; i < 4; ++i) {
        int row = (wid * 4 + i) * 2 + (l >> 5);
        int o   = (l & 31) * 16;
        gro[i]  = row * 128 + (l & 31) * 4;            // float offset
        dwo[i]  = row * 512 + (o ^ ((row & 7) << 4));  // byte offset
    }

    float bqv[2];
#pragma unroll
    for (int ct = 0; ct < 2; ++ct)
        bqv[ct] = bq[cgrp * 32 + ct * 16 + r16];

    f32x4 sA[4];            // staged tile regs (16 VGPR)
    f32x4 av4[2], av4n[2];  // alpha cur/next for this wave's node (16 VGPR)

#define LOADR(Tb)                                                             \
    do {                                                                      \
        const float* gb_ = hng + (long)(Tb) * 64 * DIN;                       \
        _Pragma("unroll")                                                     \
        for (int i_ = 0; i_ < 4; ++i_)                                        \
            sA[i_] = __builtin_nontemporal_load(                              \
                (const f32x4*)(gb_ + gro[i_]));                               \
        _Pragma("unroll")                                                     \
        for (int rt_ = 0; rt_ < 2; ++rt_)                                     \
            av4n[rt_] = __builtin_nontemporal_load(                           \
                (const f32x4*)(alpha + (long)(Tb) * 64 + rgrp * 32 +          \
                               rt_ * 16 + kg * 4));                           \
    } while (0)

#define DSWRITE(s)                                                            \
    do {                                                                      \
        char* lb_ = (char*)&As[s][0];                                         \
        _Pragma("unroll")                                                     \
        for (int i_ = 0; i_ < 4; ++i_)                                        \
            *(f32x4*)(lb_ + dwo[i_]) = sA[i_];                                \
    } while (0)

#define COMPUTE(s)                                                            \
    do {                                                                      \
        _Pragma("unroll")                                                     \
        for (int rt_ = 0; rt_ < 2; ++rt_) {                                   \
            int row_ = rgrp * 32 + rt_ * 16 + r16;                            \
            int asw_ = (row_ & 7) << 4;                                       \
            const char* sb_ = (const char*)&As[s][0] + row_ * 512;            \
            _Pragma("unroll")                                                 \
            for (int kf_ = 0; kf_ < 4; ++kf_) {                               \
                int kb_ = kf_ * 128 + kg * 32;                                \
                f32x4 v0_ = *(const f32x4*)(sb_ + ((kb_ + 0) ^ asw_));        \
                f32x4 v1_ = *(const f32x4*)(sb_ + ((kb_ + 16) ^ asw_));       \
                f16x2 p0_ = pkrtz(v0_[0], v0_[1]);                            \
                f16x2 p1_ = pkrtz(v0_[2], v0_[3]);                            \
                f16x2 p2_ = pkrtz(v1_[0], v1_[1]);                            \
                f16x2 p3_ = pkrtz(v1_[2], v1_[3]);                            \
                f16x8 ah_;                                                    \
                ah_[0] = p0_[0]; ah_[1] = p0_[1];                             \
                ah_[2] = p1_[0]; ah_[3] = p1_[1];                             \
                ah_[4] = p2_[0]; ah_[5] = p2_[1];                             \
                ah_[6] = p3_[0]; ah_[7] = p3_[1];                             \
                _Pragma("unroll")                                             \
                for (int ct_ = 0; ct_ < 2; ++ct_) {                           \
                    acc[rt_][ct_] = __builtin_amdgcn_mfma_f32_16x16x32_f16(   \
                        ah_, bh[kf_][ct_], acc[rt_][ct_], 0, 0, 0);           \
                    acc[rt_][ct_] = __builtin_amdgcn_mfma_f32_16x16x32_f16(   \
                        ah_, bl[kf_][ct_], acc[rt_][ct_], 0, 0, 0);           \
                }                                                             \
            }                                                                 \
        }                                                                     \
    } while (0)

    long t = blockIdx.x;

    // ---- prologue: load tile t to regs, write buf0 (auto vmcnt waits)
    LOADR(t);
    DSWRITE(0);
#pragma unroll
    for (int rt = 0; rt < 2; ++rt) av4[rt] = av4n[rt];
    asm volatile("s_waitcnt lgkmcnt(0)" ::: "memory");
    __builtin_amdgcn_s_barrier();
    __builtin_amdgcn_sched_barrier(0);

    int cur = 0;
    for (;;) {
        const bool last = (t + GG >= NT);
        const long tn   = last ? t : t + GG;   // clamped prefetch target

        // ---- issue next tile's loads first (overlap compute below)
        LOADR(tn);
        __builtin_amdgcn_sched_barrier(0);

        f32x4 acc[2][2];
#pragma unroll
        for (int i = 0; i < 2; ++i)
#pragma unroll
            for (int j = 0; j < 2; ++j) acc[i][j] = (f32x4){0.f, 0.f, 0.f, 0.f};

        COMPUTE(cur);
        __builtin_amdgcn_sched_barrier(0);

        // ---- epilogue: +bq, leaky, *alpha, reduce this wave's node
        {
            float part[2] = {0.f, 0.f};
            float apart = 0.f;
#pragma unroll
            for (int rt = 0; rt < 2; ++rt)
#pragma unroll
                for (int r = 0; r < 4; ++r) {
                    float aw = av4[rt][r];
                    apart += aw;
#pragma unroll
                    for (int ct = 0; ct < 2; ++ct) {
                        float v = acc[rt][ct][r] + bqv[ct];
                        v = (v >= 0.f) ? v : NEG_SLOPE * v;
                        part[ct] += aw * v;
                    }
                }
            apart += __shfl_xor(apart, 16);
            apart += __shfl_xor(apart, 32);
#pragma unroll
            for (int ct = 0; ct < 2; ++ct) {
                part[ct] += __shfl_xor(part[ct], 16);
                part[ct] += __shfl_xor(part[ct], 32);
            }
            if (l < 16) {
                long node = t * 2 + rgrp;
                float den = apart;
                if (den == 0.f) den = 1.f;
#pragma unroll
                for (int ct = 0; ct < 2; ++ct)
                    hagg[node * DHID + cgrp * 32 + ct * 16 + l] =
                        part[ct] / den;
            }
        }
        __builtin_amdgcn_sched_barrier(0);

        // ---- write next tile into the other buffer (compiler inserts the
        //      vmcnt wait on sA deps); publish with lgkm0 + barrier.
        DSWRITE(cur ^ 1);
#pragma unroll
        for (int rt = 0; rt < 2; ++rt) av4[rt] = av4n[rt];
        asm volatile("s_waitcnt lgkmcnt(0)" ::: "memory");
        __builtin_amdgcn_s_barrier();
        __builtin_amdgcn_sched_barrier(0);

        if (last) break;
        t   = tn;
        cur ^= 1;
    }
    asm volatile("s_waitcnt vmcnt(0)" ::: "memory");  // drain stores

#undef LOADR
#undef DSWRITE
#undef COMPUTE
}

// ---------------------------------------------------------------- kernel 2
// GEMM2: out = normalize(leaky(concat(h_node, hagg) @ Ww^T + bw))
// Tile: 128 nodes x 128 out, K=256 in 8 chunks of 32. hagg lives in `out`.
// A single-f16 via pkrtz; B hi+lo; 2 MFMA terms. (unchanged)
__global__ __launch_bounds__(256, 2) void gemm2_norm(
    const float* __restrict__ hnode,  // [NNODES][128]
    const float* __restrict__ bw,     // [128]
    const _Float16* __restrict__ ws,
    float* __restrict__ out)          // [NNODES][128], holds hagg on entry
{
    __shared__ _Float16 Ahi[8 * 520];
    __shared__ _Float16 Bhi[8 * 512];
    __shared__ _Float16 Blo[8 * 512];
    __shared__ float bw_s[128];
    __shared__ float nbuf[2][128];

    const int tid = threadIdx.x;
    const int l   = tid & 63;
    const int wid = tid >> 6;
    const int wr  = wid >> 1, wc = wid & 1;
    const long NB = (long)blockIdx.x * 128;

    if (tid < 128) bw_s[tid] = bw[tid];

    f32x4 acc[4][4];
#pragma unroll
    for (int i = 0; i < 4; ++i)
#pragma unroll
        for (int j = 0; j < 4; ++j) acc[i][j] = (f32x4){0.f, 0.f, 0.f, 0.f};

    const _Float16* wwh = ws + WS_WW_HI;
    const _Float16* wwl = ws + WS_WW_LO;

    for (int c = 0; c < 8; ++c) {
        __syncthreads();
        // ---- stage A: 128 nodes x 32 k of concat(h_node, hagg), f16 single
#pragma unroll
        for (int p = 0; p < 4; ++p) {
            int rl = p * 32 + (tid >> 3);
            long n = NB + rl;
            if (n > NNODES - 1) n = NNODES - 1;  // tail clamp (stores guarded)
            int kw = (tid & 7) * 4;       // within-chunk k
            int kgl = c * 32 + kw;        // global k in 0..255
            const float* g = (kgl < 128) ? (hnode + n * DIN + kgl)
                                         : (out + n * DHID + (kgl - 128));
            f32x4 v = *(const f32x4*)g;
            f16x2 p0 = pkrtz(v[0], v[1]);
            f16x2 p1 = pkrtz(v[2], v[3]);
            f16x4 vh;
            vh[0] = p0[0]; vh[1] = p0[1]; vh[2] = p1[0]; vh[3] = p1[1];
            int lw  = (rl & 15) | (((kw >> 3) & 3) << 4);
            int s   = rl >> 4;
            int off = s * 520 + lw * 8 + (kw & 7);
            *(f16x4*)(Ahi + off) = vh;
        }
        // ---- stage B slabs (g = c)
#pragma unroll
        for (int i = 0; i < 4; ++i) {
            int id = i * 256 + tid;
            int sb = id >> 6;
            int ls = id & 63;
            if (sb < 8) {
                *(f16x8*)(Bhi + sb * 512 + ls * 8) =
                    *(const f16x8*)(wwh + ((sb * 8 + c) * 64 + ls) * 8);
            } else {
                int ct = sb - 8;
                *(f16x8*)(Blo + ct * 512 + ls * 8) =
                    *(const f16x8*)(wwl + ((ct * 8 + c) * 64 + ls) * 8);
            }
        }
        __syncthreads();
        // ---- compute
        f16x8 ah[4], bh[4], bl[4];
#pragma unroll
        for (int rt = 0; rt < 4; ++rt) {
            int s = wr * 4 + rt;
            ah[rt] = *(const f16x8*)(Ahi + s * 520 + l * 8);
        }
#pragma unroll
        for (int ct = 0; ct < 4; ++ct) {
            int s = wc * 4 + ct;
            bh[ct] = *(const f16x8*)(Bhi + s * 512 + l * 8);
            bl[ct] = *(const f16x8*)(Blo + s * 512 + l * 8);
        }
#pragma unroll
        for (int rt = 0; rt < 4; ++rt)
#pragma unroll
            for (int ct = 0; ct < 4; ++ct) {
                acc[rt][ct] = __builtin_amdgcn_mfma_f32_16x16x32_f16(ah[rt], bh[ct], acc[rt][ct], 0, 0, 0);
                acc[rt][ct] = __builtin_amdgcn_mfma_f32_16x16x32_f16(ah[rt], bl[ct], acc[rt][ct], 0, 0, 0);
            }
    }

    // ---- epilogue: +bw, leaky, row L2-norm (128 cols), safediv, store
    const int grp = l >> 4;
#pragma unroll
    for (int rt = 0; rt < 4; ++rt)
#pragma unroll
        for (int ct = 0; ct < 4; ++ct)
#pragma unroll
            for (int r = 0; r < 4; ++r) {
                int col = wc * 64 + ct * 16 + (l & 15);
                float v = acc[rt][ct][r] + bw_s[col];
                acc[rt][ct][r] = (v >= 0.f) ? v : NEG_SLOPE * v;
            }
    float ssq[4][4];
#pragma unroll
    for (int rt = 0; rt < 4; ++rt)
#pragma unroll
        for (int r = 0; r < 4; ++r) {
            float s = 0.f;
#pragma unroll
            for (int ct = 0; ct < 4; ++ct) s += acc[rt][ct][r] * acc[rt][ct][r];
            s += __shfl_xor(s, 1);
            s += __shfl_xor(s, 2);
            s += __shfl_xor(s, 4);
            s += __shfl_xor(s, 8);
            ssq[rt][r] = s;  // sum over this wave's 64 cols
        }
    if ((l & 15) == 0) {
#pragma unroll
        for (int rt = 0; rt < 4; ++rt)
#pragma unroll
            for (int r = 0; r < 4; ++r)
                nbuf[wc][wr * 64 + rt * 16 + grp * 4 + r] = ssq[rt][r];
    }
    __syncthreads();
#pragma unroll
    for (int rt = 0; rt < 4; ++rt)
#pragma unroll
        for (int r = 0; r < 4; ++r) {
            int rowl = wr * 64 + rt * 16 + grp * 4 + r;
            long n = NB + rowl;
            if (n < NNODES) {
                float nrm = sqrtf(nbuf[0][rowl] + nbuf[1][rowl]);
                if (nrm == 0.f) nrm = 1.f;
#pragma unroll
                for (int ct = 0; ct < 4; ++ct) {
                    int col = wc * 64 + ct * 16 + (l & 15);
                    out[n * DOUT + col] = acc[rt][ct][r] / nrm;
                }
            }
        }
}

// ---------------------------------------------------------------- launcher
extern "C" void kernel_launch(void* const* d_in, const int* in_sizes, int n_in,
                              void* d_out, int out_size, void* d_ws, size_t ws_size,
                              hipStream_t stream) {
    const float* h_node  = (const float*)d_in[0];
    const float* h_ngbrs = (const float*)d_in[1];
    const float* alpha   = (const float*)d_in[2];
    const float* Wq      = (const float*)d_in[3];
    const float* bq      = (const float*)d_in[4];
    const float* Ww      = (const float*)d_in[5];
    const float* bw      = (const float*)d_in[6];
    float* out   = (float*)d_out;
    _Float16* ws = (_Float16*)d_ws;

    convert_weights<<<24, 256, 0, stream>>>(Wq, Ww, ws);
    gemm1_agg<<<GG, 512, 0, stream>>>(h_ngbrs, alpha, bq, ws, out);
    // ceil(50000/128) = 391 node tiles
    gemm2_norm<<<391, 256, 0, stream>>>(h_node, bw, ws, out);
}